// Round 1
// 743.030 us; speedup vs baseline: 1.0753x; 1.0753x over previous
//
#include <hip/hip_runtime.h>
#include <math.h>

// ---------------------------------------------------------------------------
// Problem constants
// ---------------------------------------------------------------------------
#define EPS_ 1e-5f

// workspace layout (float offsets)
#define WS_PART   ((size_t)0)         // 2048*256
#define WS_CTX    ((size_t)524288)    // 256
#define WS_QP     ((size_t)524544)    // 27*256
#define WS_KP     ((size_t)531456)    // 27*256
#define WS_VP     ((size_t)538368)    // 27*256
#define WS_F      ((size_t)545280)    // 864*256
#define WS_ATTN   ((size_t)766464)    // 864*256 (aout)
#define WS_H      ((size_t)987648)    // 864*2048 ushort = 884736 f32 slots
#define WS_WKB    ((size_t)1872384)   // 256*256 ushort (la_wk^T bf16)
#define WS_WVB    ((size_t)1905152)   // 256*256 ushort (la_wv^T bf16)
#define WS_WOT    ((size_t)1937920)   // 256*256 ushort (mha_wo^T bf16)
#define WS_LAQT   ((size_t)1970688)   // 256*256 ushort (la_wq^T bf16)
#define WS_W1T    ((size_t)2003456)   // 2048*256 ushort
#define WS_W2T    ((size_t)2265600)   // 256*2048 ushort
#define WS_MT     ((size_t)2527744)   // 8*32*256 ushort (wq@kp^T, scaled)
#define WS_VPT    ((size_t)2560512)   // 8*32*32 ushort
#define WS_CST    ((size_t)2564608)   // 256 f32

typedef short bf16x8 __attribute__((ext_vector_type(8)));
typedef float f32x4 __attribute__((ext_vector_type(4)));

__device__ __forceinline__ unsigned short f2bf(float f) {
    union { float f; unsigned u; } v; v.f = f;
    unsigned u = v.u;
    unsigned r = u + 0x7fffu + ((u >> 16) & 1u);   // RNE
    return (unsigned short)(r >> 16);
}
__device__ __forceinline__ float bf2f(unsigned short s) {
    union { unsigned u; float f; } v; v.u = ((unsigned)s) << 16;
    return v.f;
}
__device__ __forceinline__ bf16x8 cvt8(const float* p) {
    float4 u = ((const float4*)p)[0];
    float4 v = ((const float4*)p)[1];
    bf16x8 r;
    r[0] = (short)f2bf(u.x); r[1] = (short)f2bf(u.y);
    r[2] = (short)f2bf(u.z); r[3] = (short)f2bf(u.w);
    r[4] = (short)f2bf(v.x); r[5] = (short)f2bf(v.y);
    r[6] = (short)f2bf(v.z); r[7] = (short)f2bf(v.w);
    return r;
}
__device__ __forceinline__ bf16x8 cvt8sum(const float* p, const float* q) {
    float4 u = ((const float4*)p)[0];
    float4 v = ((const float4*)p)[1];
    float4 a = ((const float4*)q)[0];
    float4 b = ((const float4*)q)[1];
    bf16x8 r;
    r[0] = (short)f2bf(u.x + a.x); r[1] = (short)f2bf(u.y + a.y);
    r[2] = (short)f2bf(u.z + a.z); r[3] = (short)f2bf(u.w + a.w);
    r[4] = (short)f2bf(v.x + b.x); r[5] = (short)f2bf(v.y + b.y);
    r[6] = (short)f2bf(v.z + b.z); r[7] = (short)f2bf(v.w + b.w);
    return r;
}

// ---------------------------------------------------------------------------
// Setup: transpose weights to bf16 [n][k] layouts via LDS 64x64 tiles
// (coalesced on both sides). grid 320, block 256.
//   blocks   0..63  : four 256x256 mats (16 tiles each)
//   blocks  64..191 : ff_w1  (src 256x2048 -> dst 2048x256), 4x32 tiles
//   blocks 192..319 : ff_w2  (src 2048x256 -> dst 256x2048), 32x4 tiles
// ---------------------------------------------------------------------------
__global__ __launch_bounds__(256) void k_trans(const float* __restrict__ la_wk,
                                               const float* __restrict__ la_wv,
                                               const float* __restrict__ mha_wo,
                                               const float* __restrict__ la_wq,
                                               const float* __restrict__ ff_w1,
                                               const float* __restrict__ ff_w2,
                                               unsigned short* __restrict__ wkb,
                                               unsigned short* __restrict__ wvb,
                                               unsigned short* __restrict__ woT,
                                               unsigned short* __restrict__ laqT,
                                               unsigned short* __restrict__ w1T,
                                               unsigned short* __restrict__ w2T) {
    __shared__ float T[64][65];
    int id = blockIdx.x, t = threadIdx.x;
    const float* src; unsigned short* dst; int R, C, tr, tc;
    if (id < 64) {
        int task = id >> 4, tile = id & 15;
        R = 256; C = 256; tr = tile >> 2; tc = tile & 3;
        src = task == 0 ? la_wk : task == 1 ? la_wv : task == 2 ? mha_wo : la_wq;
        dst = task == 0 ? wkb : task == 1 ? wvb : task == 2 ? woT : laqT;
    } else if (id < 192) {
        int tile = id - 64;
        R = 256; C = 2048; tr = tile >> 5; tc = tile & 31;
        src = ff_w1; dst = w1T;
    } else {
        int tile = id - 192;
        R = 2048; C = 256; tr = tile >> 2; tc = tile & 3;
        src = ff_w2; dst = w2T;
    }
    int r0 = tr * 64, c0 = tc * 64;
    int i = t >> 2, j0 = (t & 3) * 16;
    const float* s = src + (size_t)(r0 + i) * C + c0 + j0;
#pragma unroll
    for (int k = 0; k < 4; ++k) {
        float4 v = ((const float4*)s)[k];
        T[i][j0 + 4 * k + 0] = v.x;
        T[i][j0 + 4 * k + 1] = v.y;
        T[i][j0 + 4 * k + 2] = v.z;
        T[i][j0 + 4 * k + 3] = v.w;
    }
    __syncthreads();
    unsigned short o[16];
#pragma unroll
    for (int k = 0; k < 16; ++k) o[k] = f2bf(T[j0 + k][i]);
    unsigned short* d = dst + (size_t)(c0 + i) * R + r0 + j0;
    ((uint4*)d)[0] = *(const uint4*)&o[0];
    ((uint4*)d)[1] = *(const uint4*)&o[8];
}

// ---------------------------------------------------------------------------
// Phase A GEMM, v2: one barrier per K-tile, register prefetch of f_e(t+1)
// and pos(t) issued BEFORE the barrier (the pre-barrier vmcnt drain absorbs
// the latency), weights loaded as fragments directly from L2, X-fragment
// built in registers (no lx LDS round-trip). Math identical to v1.
// grid 2048 (b*64 + pt*2 + et), block 256 (4 waves, 2x2).
// ---------------------------------------------------------------------------
__global__ __launch_bounds__(256, 2) void pa_gemm(const float* __restrict__ f_e,
                                                  const float* __restrict__ pos_emb,
                                                  const unsigned short* __restrict__ wkb,
                                                  const unsigned short* __restrict__ wvb,
                                                  const float* __restrict__ bk,
                                                  const float* __restrict__ bv,
                                                  float* __restrict__ part) {
    __shared__ __align__(16) unsigned short lv[2][128 * 40];
    __shared__ float reds[2 * 128];
    __shared__ float redt[2 * 128];

    const int g  = blockIdx.x;
    const int et = g & 1;
    const int pt = (g >> 1) & 31;
    const int b  = g >> 6;
    const int p0 = pt * 128;
    const int e0 = et * 128;

    const int tid  = threadIdx.x;
    const int wave = tid >> 6;
    const int lane = tid & 63;
    const int quad = lane >> 4;
    const int l15  = lane & 15;
    const int wm = wave >> 1;
    const int wn = wave & 1;

    f32x4 accx[4][4], accv[4][4];
    const f32x4 zero4 = {0.f, 0.f, 0.f, 0.f};
#pragma unroll
    for (int i = 0; i < 4; ++i)
#pragma unroll
        for (int j = 0; j < 4; ++j) { accx[i][j] = zero4; accv[i][j] = zero4; }

    const int sk  = tid >> 3;          // e-local 0..31
    const int sm0 = (tid & 7) << 4;    // p offset 0..112

    const float* feb = f_e + (size_t)b * (256 * 4096) + p0;
    // lane-fixed bases
    const float* posb = pos_emb + ((size_t)(p0 + wm * 64 + l15) * 32 + b) * 256 + quad * 8;
    const unsigned short* wkp = wkb + (size_t)(e0 + wn * 64 + l15) * 256 + quad * 8;
    const unsigned short* wvp = wvb + (size_t)(e0 + wn * 64 + l15) * 256 + quad * 8;

    // prologue: load f_e tile 0 into regs
    float4 pf[4];
    {
        const float* src = feb + (size_t)sk * 4096 + sm0;
#pragma unroll
        for (int i = 0; i < 4; ++i) pf[i] = ((const float4*)src)[i];
    }

#pragma unroll 1
    for (int kt = 0; kt < 8; ++kt) {
        const int c0 = kt * 32;
        unsigned short* L = lv[kt & 1];
        // stage current tile: regs -> bf16 -> LDS (transposed [p][e])
#pragma unroll
        for (int i = 0; i < 4; ++i) {
            L[(sm0 + 4 * i + 0) * 40 + sk] = f2bf(pf[i].x);
            L[(sm0 + 4 * i + 1) * 40 + sk] = f2bf(pf[i].y);
            L[(sm0 + 4 * i + 2) * 40 + sk] = f2bf(pf[i].z);
            L[(sm0 + 4 * i + 3) * 40 + sk] = f2bf(pf[i].w);
        }
        // prefetch next f_e tile (drains at the barrier, no post-barrier stall)
        float4 nf[4];
        if (kt < 7) {
            const float* src = feb + (size_t)(c0 + 32 + sk) * 4096 + sm0;
#pragma unroll
            for (int i = 0; i < 4; ++i) nf[i] = ((const float4*)src)[i];
        }
        // prefetch this tile's pos fragments (8 f32 per ms)
        float4 pp[4][2];
#pragma unroll
        for (int ms = 0; ms < 4; ++ms) {
            const float* p = posb + (size_t)ms * (16 * 32 * 256) + c0;
            pp[ms][0] = ((const float4*)p)[0];
            pp[ms][1] = ((const float4*)p)[1];
        }
        __syncthreads();
        // weight fragments straight from global (L2-resident, 256KB total)
        bf16x8 fk[4], fv[4];
#pragma unroll
        for (int ns = 0; ns < 4; ++ns) {
            fk[ns] = *(const bf16x8*)(wkp + (size_t)ns * (16 * 256) + c0);
            fv[ns] = *(const bf16x8*)(wvp + (size_t)ns * (16 * 256) + c0);
        }
#pragma unroll
        for (int ms = 0; ms < 4; ++ms) {
            int row = wm * 64 + ms * 16 + l15;
            uint4 avu = *(const uint4*)&L[row * 40 + quad * 8];
            bf16x8 av = *(const bf16x8*)&avu;
            // X fragment = bf16(f32(V) + pos)  (identical to old lv->lx math)
            bf16x8 ax;
            ax[0] = (short)f2bf(__uint_as_float(avu.x << 16)          + pp[ms][0].x);
            ax[1] = (short)f2bf(__uint_as_float(avu.x & 0xffff0000u)  + pp[ms][0].y);
            ax[2] = (short)f2bf(__uint_as_float(avu.y << 16)          + pp[ms][0].z);
            ax[3] = (short)f2bf(__uint_as_float(avu.y & 0xffff0000u)  + pp[ms][0].w);
            ax[4] = (short)f2bf(__uint_as_float(avu.z << 16)          + pp[ms][1].x);
            ax[5] = (short)f2bf(__uint_as_float(avu.z & 0xffff0000u)  + pp[ms][1].y);
            ax[6] = (short)f2bf(__uint_as_float(avu.w << 16)          + pp[ms][1].z);
            ax[7] = (short)f2bf(__uint_as_float(avu.w & 0xffff0000u)  + pp[ms][1].w);
#pragma unroll
            for (int ns = 0; ns < 4; ++ns) {
                accx[ms][ns] = __builtin_amdgcn_mfma_f32_16x16x32_bf16(ax, fk[ns], accx[ms][ns], 0, 0, 0);
                accv[ms][ns] = __builtin_amdgcn_mfma_f32_16x16x32_bf16(av, fv[ns], accv[ms][ns], 0, 0, 0);
            }
        }
        if (kt < 7) {
#pragma unroll
            for (int i = 0; i < 4; ++i) pf[i] = nf[i];
        }
    }

#pragma unroll
    for (int ns = 0; ns < 4; ++ns) {
        int nloc = wn * 64 + ns * 16 + l15;
        float bkv = bk[e0 + nloc];
        float bvv = bv[e0 + nloc];
        float ps = 0.f, pt_ = 0.f;
#pragma unroll
        for (int ms = 0; ms < 4; ++ms)
#pragma unroll
            for (int r = 0; r < 4; ++r) {
                float ex = __expf(accx[ms][ns][r] + bkv);
                float vv = accv[ms][ns][r] + bvv;
                ps += ex;
                pt_ += ex * vv;
            }
        ps  += __shfl_xor(ps, 16);  ps  += __shfl_xor(ps, 32);
        pt_ += __shfl_xor(pt_, 16); pt_ += __shfl_xor(pt_, 32);
        if (lane < 16) { reds[wm * 128 + nloc] = ps; redt[wm * 128 + nloc] = pt_; }
    }
    __syncthreads();
    if (tid < 128) {
        float s = reds[tid] + reds[128 + tid];
        float t = redt[tid] + redt[128 + tid];
        part[(size_t)g * 256 + tid] = s;
        part[(size_t)g * 256 + 128 + tid] = t;
    }
}

__global__ __launch_bounds__(256) void pa_reduce(const float* __restrict__ part,
                                                 float* __restrict__ ctx) {
    int e = blockIdx.x, tid = threadIdx.x;
    int et = e >> 7, n = e & 127;
    float s = 0.f, t = 0.f;
#pragma unroll
    for (int j = 0; j < 4; ++j) {
        int q = tid * 4 + j;
        const float* p = part + (size_t)(q * 2 + et) * 256 + n;
        s += p[0];
        t += p[128];
    }
    int wave = tid >> 6, lane = tid & 63;
#pragma unroll
    for (int o = 1; o < 64; o <<= 1) { s += __shfl_xor(s, o); t += __shfl_xor(t, o); }
    __shared__ float rs[4], rt[4];
    if (lane == 0) { rs[wave] = s; rt[wave] = t; }
    __syncthreads();
    if (tid == 0) {
        float S = rs[0] + rs[1] + rs[2] + rs[3];
        float T = rt[0] + rt[1] + rt[2] + rt[3];
        ctx[e] = T / S;
    }
}

// ---------------------------------------------------------------------------
// Query positional encoding qp[27][256]. grid 27, block 256.
// ---------------------------------------------------------------------------
__global__ __launch_bounds__(256) void k_qpos(float* __restrict__ qp) {
    int n = blockIdx.x, e = threadIdx.x;
    int q9 = n % 9;
    int y = q9 / 3, x = q9 % 3;
    float pos; int idx;
    if (e < 128) { pos = (float)(y + 1); idx = e; }
    else         { pos = (float)(x + 1); idx = e - 128; }
    int j = idx >> 1;
    float inv = expf(-(float)j * 0.14391156831212787f);
    float arg = pos * inv;
    qp[(size_t)n * 256 + e] = (idx & 1) ? cosf(arg) : sinf(arg);
}

// kp/vp = shape_map @ mha_wk/wv + b. grid 54, block 256.
__global__ __launch_bounds__(256) void k_kvproj(const float* __restrict__ sm,
                                                const float* __restrict__ wk,
                                                const float* __restrict__ bk,
                                                const float* __restrict__ wv,
                                                const float* __restrict__ bv,
                                                float* __restrict__ kp,
                                                float* __restrict__ vp) {
    int g = blockIdx.x;
    int n = g % 27, which = g / 27;
    int e = threadIdx.x;
    const float* W = which ? wv : wk;
    const float* B = which ? bv : bk;
    float* O = which ? vp : kp;
    const float* row = sm + (size_t)n * 256;
    float acc = 0.f;
    for (int c = 0; c < 256; ++c) acc += row[c] * W[(size_t)c * 256 + e];
    O[(size_t)n * 256 + e] = acc + B[e];
}

// MT[h][s][c] = scale * sum_d wq[c][h*32+d]*kp[s][h*32+d]; cst[h][s] likewise for bq.
// grid 256 (h*32+s), block 256 (c)
__global__ __launch_bounds__(256) void k_mt(const float* __restrict__ wq,
                                            const float* __restrict__ bq,
                                            const float* __restrict__ kp,
                                            unsigned short* __restrict__ MT,
                                            float* __restrict__ cst) {
    int h = blockIdx.x >> 5, s = blockIdx.x & 31;
    int c = threadIdx.x;
    const float SC = 0.17677669529663687f;   // 1/sqrt(32)
    if (s < 27) {
        float a = 0.f;
#pragma unroll
        for (int d = 0; d < 32; ++d)
            a += wq[(size_t)c * 256 + h * 32 + d] * kp[(size_t)s * 256 + h * 32 + d];
        MT[((size_t)(h * 32 + s)) * 256 + c] = f2bf(a * SC);
        if (c == 0) {
            float cb = 0.f;
#pragma unroll
            for (int d = 0; d < 32; ++d) cb += bq[h * 32 + d] * kp[(size_t)s * 256 + h * 32 + d];
            cst[h * 32 + s] = cb * SC;
        }
    } else {
        MT[((size_t)(h * 32 + s)) * 256 + c] = 0;
        if (c == 0) cst[h * 32 + s] = -1e30f;
    }
}

// vpT[h][d][s] = bf16(vp[s][h*32+d]) (s>=27 -> 0). grid 8, block 256.
__global__ __launch_bounds__(256) void k_vpt(const float* __restrict__ vp,
                                             unsigned short* __restrict__ vpT) {
    int h = blockIdx.x, t = threadIdx.x;
    int s = t & 31;
#pragma unroll
    for (int i = 0; i < 4; ++i) {
        int d = (t >> 5) + 8 * i;
        vpT[((size_t)(h * 32 + d)) * 32 + s] = (s < 27) ? f2bf(vp[(size_t)s * 256 + h * 32 + d]) : (unsigned short)0;
    }
}

// F0[r][e] = shape_map[r>>5][e]. grid 864, block 256.
__global__ __launch_bounds__(256) void k_finit(const float* __restrict__ sm,
                                               float* __restrict__ F) {
    int r = blockIdx.x, e = threadIdx.x;
    F[(size_t)r * 256 + e] = sm[(size_t)(r >> 5) * 256 + e];
}

// ---------------------------------------------------------------------------
// B1: fused qproj + attention per (b,h). grid 256, block 256 (4 waves).
// scores = (F+qp) @ MT_h + cst_h  (K=256, MFMA); softmax rows; out = P @ vpT_h.
// ---------------------------------------------------------------------------
__global__ __launch_bounds__(256) void b1_attn(const float* __restrict__ F,
                                               const float* __restrict__ qp,
                                               const unsigned short* __restrict__ MT,
                                               const float* __restrict__ cst,
                                               const unsigned short* __restrict__ vpT,
                                               float* __restrict__ aout) {
    __shared__ float S[32][33];
    __shared__ __align__(16) unsigned short Pb[32][40];
    int b = blockIdx.x >> 3, h = blockIdx.x & 7;
    int tid = threadIdx.x, wave = tid >> 6, lane = tid & 63;
    int quad = lane >> 4, l15 = lane & 15;
    int lt = wave >> 1, st = wave & 1;
    const f32x4 z4 = {0.f, 0.f, 0.f, 0.f};
    f32x4 acc = z4;
    int l = lt * 16 + l15;
    bool lok = (l < 27);
    const float* xF = F + (size_t)(l * 32 + b) * 256;
    const float* xq = qp + (size_t)l * 256;
    const unsigned short* Bp = MT + (size_t)(h * 32 + st * 16 + l15) * 256;
#pragma unroll
    for (int kt = 0; kt < 8; ++kt) {
        int c = kt * 32 + quad * 8;
        bf16x8 a;
        if (lok) a = cvt8sum(xF + c, xq + c);
        else {
#pragma unroll
            for (int i = 0; i < 8; ++i) a[i] = 0;
        }
        bf16x8 bb = *(const bf16x8*)(Bp + c);
        acc = __builtin_amdgcn_mfma_f32_16x16x32_bf16(a, bb, acc, 0, 0, 0);
    }
    float cstv = cst[h * 32 + st * 16 + l15];
#pragma unroll
    for (int r = 0; r < 4; ++r) S[lt * 16 + quad * 4 + r][st * 16 + l15] = acc[r] + cstv;
    __syncthreads();
    if (tid < 32) {
        float pv[32];
        float m = -1e30f;
#pragma unroll
        for (int s = 0; s < 32; ++s) { pv[s] = S[tid][s]; m = fmaxf(m, pv[s]); }
        float sum = 0.f;
#pragma unroll
        for (int s = 0; s < 32; ++s) { pv[s] = __expf(pv[s] - m); sum += pv[s]; }
        float inv = 1.f / sum;
#pragma unroll
        for (int s = 0; s < 32; ++s) Pb[tid][s] = f2bf(pv[s] * inv);
    }
    __syncthreads();
    bf16x8 a2 = *(const bf16x8*)&Pb[lt * 16 + l15][quad * 8];
    bf16x8 b2 = *(const bf16x8*)(vpT + (size_t)(h * 32 + st * 16 + l15) * 32 + quad * 8);
    f32x4 o = __builtin_amdgcn_mfma_f32_16x16x32_bf16(a2, b2, z4, 0, 0, 0);
#pragma unroll
    for (int r = 0; r < 4; ++r) {
        int ll = lt * 16 + quad * 4 + r;
        if (ll < 27) aout[(size_t)(ll * 32 + b) * 256 + h * 32 + st * 16 + l15] = o[r];
    }
}

// ---------------------------------------------------------------------------
// B2: fused oproj + LN1 + linear-attn + LN2 for 16-row tile. grid 54, block 256.
// ---------------------------------------------------------------------------
__global__ __launch_bounds__(256) void b2_mid(const float* __restrict__ aout,
                                              const unsigned short* __restrict__ woT,
                                              const float* __restrict__ bo,
                                              float* __restrict__ F,
                                              const float* __restrict__ g1,
                                              const float* __restrict__ b1v,
                                              const float* __restrict__ qp,
                                              const unsigned short* __restrict__ laqT,
                                              const float* __restrict__ labq,
                                              const float* __restrict__ ctx,
                                              const float* __restrict__ g2,
                                              const float* __restrict__ b2v) {
    __shared__ __align__(16) unsigned short X1b[16][264];
    __shared__ float r1s[4][16], r1q[4][16], rm[4][16], rp[4][16], r2s[4][16], r2q[4][16];
    int r0 = blockIdx.x * 16;
    int lrow = r0 >> 5;
    int tid = threadIdx.x, w = tid >> 6, lane = tid & 63;
    int quad = lane >> 4, l15 = lane & 15;
    const f32x4 z4 = {0.f, 0.f, 0.f, 0.f};
    f32x4 acc[4] = {z4, z4, z4, z4};
    const float* Ap = aout + (size_t)(r0 + l15) * 256;
#pragma unroll
    for (int kt = 0; kt < 8; ++kt) {
        int c = kt * 32 + quad * 8;
        bf16x8 a = cvt8(Ap + c);
#pragma unroll
        for (int nt = 0; nt < 4; ++nt) {
            bf16x8 bb = *(const bf16x8*)(woT + (size_t)(w * 64 + nt * 16 + l15) * 256 + c);
            acc[nt] = __builtin_amdgcn_mfma_f32_16x16x32_bf16(a, bb, acc[nt], 0, 0, 0);
        }
    }
    int e_[4];
#pragma unroll
    for (int nt = 0; nt < 4; ++nt) e_[nt] = w * 64 + nt * 16 + l15;
    float val[4][4];
#pragma unroll
    for (int nt = 0; nt < 4; ++nt) {
        float bov = bo[e_[nt]];
#pragma unroll
        for (int r = 0; r < 4; ++r) {
            int row = quad * 4 + r;
            val[nt][r] = acc[nt][r] + bov + F[(size_t)(r0 + row) * 256 + e_[nt]];
        }
    }
    // LN1 reduce
#pragma unroll
    for (int r = 0; r < 4; ++r) {
        float s = val[0][r] + val[1][r] + val[2][r] + val[3][r];
        float q = val[0][r] * val[0][r] + val[1][r] * val[1][r] + val[2][r] * val[2][r] + val[3][r] * val[3][r];
#pragma unroll
        for (int o = 1; o < 16; o <<= 1) { s += __shfl_xor(s, o); q += __shfl_xor(q, o); }
        if (l15 == 0) { r1s[w][quad * 4 + r] = s; r1q[w][quad * 4 + r] = q; }
    }
    __syncthreads();
#pragma unroll
    for (int r = 0; r < 4; ++r) {
        int row = quad * 4 + r;
        float S = r1s[0][row] + r1s[1][row] + r1s[2][row] + r1s[3][row];
        float Q = r1q[0][row] + r1q[1][row] + r1q[2][row] + r1q[3][row];
        float mean = S * (1.f / 256.f);
        float var  = Q * (1.f / 256.f) - mean * mean;
        float rs   = rsqrtf(var + EPS_);
#pragma unroll
        for (int nt = 0; nt < 4; ++nt) {
            int e = e_[nt];
            float f1 = (val[nt][r] - mean) * rs * g1[e] + b1v[e];
            X1b[row][e] = f2bf(f1 + qp[(size_t)lrow * 256 + e]);
            val[nt][r] = f1;   // keep F1 in regs for residual
        }
    }
    __syncthreads();
    // GEMM2: (F1+qp) @ la_wq
    f32x4 acc2[4] = {z4, z4, z4, z4};
#pragma unroll
    for (int kt = 0; kt < 8; ++kt) {
        int c = kt * 32 + quad * 8;
        bf16x8 a = *(const bf16x8*)&X1b[l15][c];
#pragma unroll
        for (int nt = 0; nt < 4; ++nt) {
            bf16x8 bb = *(const bf16x8*)(laqT + (size_t)(w * 64 + nt * 16 + l15) * 256 + c);
            acc2[nt] = __builtin_amdgcn_mfma_f32_16x16x32_bf16(a, bb, acc2[nt], 0, 0, 0);
        }
    }
    float y[4][4];
#pragma unroll
    for (int nt = 0; nt < 4; ++nt) {
        float bqv = labq[e_[nt]];
#pragma unroll
        for (int r = 0; r < 4; ++r) y[nt][r] = (acc2[nt][r] + bqv) * 0.0625f;
    }
    // softmax over e per row: max
#pragma unroll
    for (int r = 0; r < 4; ++r) {
        float m = fmaxf(fmaxf(y[0][r], y[1][r]), fmaxf(y[2][r], y[3][r]));
#pragma unroll
        for (int o = 1; o < 16; o <<= 1) m = fmaxf(m, __shfl_xor(m, o));
        if (l15 == 0) rm[w][quad * 4 + r] = m;
    }
    __syncthreads();
    float p[4][4];
#pragma unroll
    for (int r = 0; r < 4; ++r) {
        int row = quad * 4 + r;
        float M = fmaxf(fmaxf(rm[0][row], rm[1][row]), fmaxf(rm[2][row], rm[3][row]));
        float ps = 0.f;
#pragma unroll
        for (int nt = 0; nt < 4; ++nt) { p[nt][r] = __expf(y[nt][r] - M); ps += p[nt][r]; }
#pragma unroll
        for (int o = 1; o < 16; o <<= 1) ps += __shfl_xor(ps, o);
        if (l15 == 0) rp[w][row] = ps;
    }
    __syncthreads();
#pragma unroll
    for (int r = 0; r < 4; ++r) {
        int row = quad * 4 + r;
        float Ssum = rp[0][row] + rp[1][row] + rp[2][row] + rp[3][row];
        float inv = 1.f / Ssum;
#pragma unroll
        for (int nt = 0; nt < 4; ++nt)
            val[nt][r] = val[nt][r] + (p[nt][r] * inv) * ctx[e_[nt]];
    }
    // LN2
#pragma unroll
    for (int r = 0; r < 4; ++r) {
        float s = val[0][r] + val[1][r] + val[2][r] + val[3][r];
        float q = val[0][r] * val[0][r] + val[1][r] * val[1][r] + val[2][r] * val[2][r] + val[3][r] * val[3][r];
#pragma unroll
        for (int o = 1; o < 16; o <<= 1) { s += __shfl_xor(s, o); q += __shfl_xor(q, o); }
        if (l15 == 0) { r2s[w][quad * 4 + r] = s; r2q[w][quad * 4 + r] = q; }
    }
    __syncthreads();
#pragma unroll
    for (int r = 0; r < 4; ++r) {
        int row = quad * 4 + r;
        float S = r2s[0][row] + r2s[1][row] + r2s[2][row] + r2s[3][row];
        float Q = r2q[0][row] + r2q[1][row] + r2q[2][row] + r2q[3][row];
        float mean = S * (1.f / 256.f);
        float var  = Q * (1.f / 256.f) - mean * mean;
        float rs   = rsqrtf(var + EPS_);
#pragma unroll
        for (int nt = 0; nt < 4; ++nt) {
            int e = e_[nt];
            F[(size_t)(r0 + row) * 256 + e] = (val[nt][r] - mean) * rs * g2[e] + b2v[e];
        }
    }
}

// ---------------------------------------------------------------------------
// B3: FFN1 H = gelu(F @ w1 + b1), bf16 out. grid 1728 (54 m x 32 n), block 256.
// ---------------------------------------------------------------------------
__global__ __launch_bounds__(256) void b3_ffn1(const float* __restrict__ F,
                                               const unsigned short* __restrict__ w1T,
                                               const float* __restrict__ fb1,
                                               unsigned short* __restrict__ Hb) {
    int bm = blockIdx.x >> 5, bn = blockIdx.x & 31;
    int tid = threadIdx.x, w = tid >> 6, lane = tid & 63;
    int quad = lane >> 4, l15 = lane & 15;
    int r0 = bm * 16;
    int n0 = bn * 64 + w * 16;
    const f32x4 z4 = {0.f, 0.f, 0.f, 0.f};
    f32x4 acc = z4;
    const float* Ap = F + (size_t)(r0 + l15) * 256;
    const unsigned short* Bp = w1T + (size_t)(n0 + l15) * 256;
#pragma unroll
    for (int kt = 0; kt < 8; ++kt) {
        int c = kt * 32 + quad * 8;
        bf16x8 a = cvt8(Ap + c);
        bf16x8 bb = *(const bf16x8*)(Bp + c);
        acc = __builtin_amdgcn_mfma_f32_16x16x32_bf16(a, bb, acc, 0, 0, 0);
    }
    int e = n0 + l15;
    float bv = fb1[e];
#pragma unroll
    for (int r = 0; r < 4; ++r) {
        float hh = acc[r] + bv;
        float g = 0.5f * hh * (1.f + erff(hh * 0.70710678118654752f));
        Hb[(size_t)(r0 + quad * 4 + r) * 2048 + e] = f2bf(g);
    }
}

// ---------------------------------------------------------------------------
// B4: FFN2 + bias + residual + LN3 + output write. grid 54, block 256.
// ---------------------------------------------------------------------------
__global__ __launch_bounds__(256) void b4_ffn2(const unsigned short* __restrict__ Hb,
                                               const unsigned short* __restrict__ w2T,
                                               const float* __restrict__ fb2,
                                               float* __restrict__ F,
                                               const float* __restrict__ g3,
                                               const float* __restrict__ b3v,
                                               float* __restrict__ out,
                                               int step) {
    __shared__ float r3s[4][16], r3q[4][16];
    int r0 = blockIdx.x * 16;
    int tid = threadIdx.x, w = tid >> 6, lane = tid & 63;
    int quad = lane >> 4, l15 = lane & 15;
    const f32x4 z4 = {0.f, 0.f, 0.f, 0.f};
    f32x4 acc[4] = {z4, z4, z4, z4};
    const unsigned short* Ap = Hb + (size_t)(r0 + l15) * 2048;
#pragma unroll 4
    for (int kt = 0; kt < 64; ++kt) {
        int c = kt * 32 + quad * 8;
        bf16x8 a = *(const bf16x8*)(Ap + c);
#pragma unroll
        for (int nt = 0; nt < 4; ++nt) {
            bf16x8 bb = *(const bf16x8*)(w2T + (size_t)(w * 64 + nt * 16 + l15) * 2048 + c);
            acc[nt] = __builtin_amdgcn_mfma_f32_16x16x32_bf16(a, bb, acc[nt], 0, 0, 0);
        }
    }
    int e_[4];
#pragma unroll
    for (int nt = 0; nt < 4; ++nt) e_[nt] = w * 64 + nt * 16 + l15;
    float val[4][4];
#pragma unroll
    for (int nt = 0; nt < 4; ++nt) {
        float bv = fb2[e_[nt]];
#pragma unroll
        for (int r = 0; r < 4; ++r) {
            int row = quad * 4 + r;
            val[nt][r] = acc[nt][r] + bv + F[(size_t)(r0 + row) * 256 + e_[nt]];
        }
    }
#pragma unroll
    for (int r = 0; r < 4; ++r) {
        float s = val[0][r] + val[1][r] + val[2][r] + val[3][r];
        float q = val[0][r] * val[0][r] + val[1][r] * val[1][r] + val[2][r] * val[2][r] + val[3][r] * val[3][r];
#pragma unroll
        for (int o = 1; o < 16; o <<= 1) { s += __shfl_xor(s, o); q += __shfl_xor(q, o); }
        if (l15 == 0) { r3s[w][quad * 4 + r] = s; r3q[w][quad * 4 + r] = q; }
    }
    __syncthreads();
#pragma unroll
    for (int r = 0; r < 4; ++r) {
        int row = quad * 4 + r;
        float S = r3s[0][row] + r3s[1][row] + r3s[2][row] + r3s[3][row];
        float Q = r3q[0][row] + r3q[1][row] + r3q[2][row] + r3q[3][row];
        float mean = S * (1.f / 256.f);
        float var  = Q * (1.f / 256.f) - mean * mean;
        float rs   = rsqrtf(var + EPS_);
#pragma unroll
        for (int nt = 0; nt < 4; ++nt) {
            int e = e_[nt];
            float o = (val[nt][r] - mean) * rs * g3[e] + b3v[e];
            F[(size_t)(r0 + row) * 256 + e] = o;
            out[(size_t)step * 221184 + (size_t)(r0 + row) * 256 + e] = o;
        }
    }
}

// ---------------------------------------------------------------------------
extern "C" void kernel_launch(void* const* d_in, const int* in_sizes, int n_in,
                              void* d_out, int out_size, void* d_ws, size_t ws_size,
                              hipStream_t stream) {
    const float* f_e     = (const float*)d_in[0];
    const float* pos_emb = (const float*)d_in[1];
    const float* sm      = (const float*)d_in[3];
    const float* mha_wq  = (const float*)d_in[4];
    const float* mha_bq  = (const float*)d_in[5];
    const float* mha_wk  = (const float*)d_in[6];
    const float* mha_bk  = (const float*)d_in[7];
    const float* mha_wv  = (const float*)d_in[8];
    const float* mha_bv  = (const float*)d_in[9];
    const float* mha_wo  = (const float*)d_in[10];
    const float* mha_bo  = (const float*)d_in[11];
    const float* la_wq   = (const float*)d_in[12];
    const float* la_bq   = (const float*)d_in[13];
    const float* la_wk   = (const float*)d_in[14];
    const float* la_bk   = (const float*)d_in[15];
    const float* la_wv   = (const float*)d_in[16];
    const float* la_bv   = (const float*)d_in[17];
    const float* ff_w1   = (const float*)d_in[18];
    const float* ff_b1   = (const float*)d_in[19];
    const float* ff_w2   = (const float*)d_in[20];
    const float* ff_b2   = (const float*)d_in[21];
    const float* n1_g    = (const float*)d_in[22];
    const float* n1_b    = (const float*)d_in[23];
    const float* n2_g    = (const float*)d_in[24];
    const float* n2_b    = (const float*)d_in[25];
    const float* n3_g    = (const float*)d_in[26];
    const float* n3_b    = (const float*)d_in[27];

    float* ws = (float*)d_ws;
    float* part = ws + WS_PART;
    float* ctx  = ws + WS_CTX;
    float* qp   = ws + WS_QP;
    float* kp   = ws + WS_KP;
    float* vp   = ws + WS_VP;
    float* F    = ws + WS_F;
    float* aout = ws + WS_ATTN;
    unsigned short* Hb   = (unsigned short*)(ws + WS_H);
    unsigned short* wkb  = (unsigned short*)(ws + WS_WKB);
    unsigned short* wvb  = (unsigned short*)(ws + WS_WVB);
    unsigned short* woT  = (unsigned short*)(ws + WS_WOT);
    unsigned short* laqT = (unsigned short*)(ws + WS_LAQT);
    unsigned short* w1T  = (unsigned short*)(ws + WS_W1T);
    unsigned short* w2T  = (unsigned short*)(ws + WS_W2T);
    unsigned short* MT   = (unsigned short*)(ws + WS_MT);
    unsigned short* vpT  = (unsigned short*)(ws + WS_VPT);
    float* cst = ws + WS_CST;

    float* out = (float*)d_out;

    // setup
    k_trans<<<320, 256, 0, stream>>>(la_wk, la_wv, mha_wo, la_wq, ff_w1, ff_w2,
                                     wkb, wvb, woT, laqT, w1T, w2T);
    k_qpos<<<27, 256, 0, stream>>>(qp);
    k_kvproj<<<54, 256, 0, stream>>>(sm, mha_wk, mha_bk, mha_wv, mha_bv, kp, vp);
    k_mt<<<256, 256, 0, stream>>>(mha_wq, mha_bq, kp, MT, cst);
    k_vpt<<<8, 256, 0, stream>>>(vp, vpT);
    k_finit<<<864, 256, 0, stream>>>(sm, F);

    // phase A
    pa_gemm<<<2048, 256, 0, stream>>>(f_e, pos_emb, wkb, wvb, la_bk, la_bv, part);
    pa_reduce<<<256, 256, 0, stream>>>(part, ctx);

    // phase B: 3 decoder steps
    for (int s = 0; s < 3; ++s) {
        b1_attn<<<256, 256, 0, stream>>>(F, qp, MT, cst, vpT, aout);
        b2_mid<<<54, 256, 0, stream>>>(aout, woT, mha_bo, F, n1_g, n1_b, qp,
                                       laqT, la_bq, ctx, n2_g, n2_b);
        b3_ffn1<<<1728, 256, 0, stream>>>(F, w1T, ff_b1, Hb);
        b4_ffn2<<<54, 256, 0, stream>>>(Hb, w2T, ff_b2, F, n3_g, n3_b, out, s);
    }
}

// Round 2
// 729.278 us; speedup vs baseline: 1.0956x; 1.0189x over previous
//
#include <hip/hip_runtime.h>
#include <math.h>

// ---------------------------------------------------------------------------
// Problem constants
// ---------------------------------------------------------------------------
#define EPS_ 1e-5f

// workspace layout (float offsets)
#define WS_PART   ((size_t)0)         // 2048*256
#define WS_CTX    ((size_t)524288)    // 256
#define WS_QP     ((size_t)524544)    // 27*256
#define WS_KP     ((size_t)531456)    // 27*256
#define WS_VP     ((size_t)538368)    // 27*256
#define WS_F      ((size_t)545280)    // 864*256
#define WS_ATTN   ((size_t)766464)    // 864*256 (aout)
#define WS_H      ((size_t)987648)    // 864*2048 ushort = 884736 f32 slots
#define WS_WKB    ((size_t)1872384)   // 256*256 ushort (la_wk^T bf16)
#define WS_WVB    ((size_t)1905152)   // 256*256 ushort (la_wv^T bf16)
#define WS_WOT    ((size_t)1937920)   // 256*256 ushort (mha_wo^T bf16)
#define WS_LAQT   ((size_t)1970688)   // 256*256 ushort (la_wq^T bf16)
#define WS_W1T    ((size_t)2003456)   // 2048*256 ushort
#define WS_W2T    ((size_t)2265600)   // 256*2048 ushort
#define WS_MT     ((size_t)2527744)   // 8*32*256 ushort (wq@kp^T, scaled)
#define WS_VPT    ((size_t)2560512)   // 8*32*32 ushort
#define WS_CST    ((size_t)2564608)   // 256 f32

typedef short bf16x8 __attribute__((ext_vector_type(8)));
typedef float f32x4 __attribute__((ext_vector_type(4)));

__device__ __forceinline__ unsigned short f2bf(float f) {
    union { float f; unsigned u; } v; v.f = f;
    unsigned u = v.u;
    unsigned r = u + 0x7fffu + ((u >> 16) & 1u);   // RNE
    return (unsigned short)(r >> 16);
}
__device__ __forceinline__ float bf2f(unsigned short s) {
    union { unsigned u; float f; } v; v.u = ((unsigned)s) << 16;
    return v.f;
}
__device__ __forceinline__ bf16x8 cvt8(const float* p) {
    float4 u = ((const float4*)p)[0];
    float4 v = ((const float4*)p)[1];
    bf16x8 r;
    r[0] = (short)f2bf(u.x); r[1] = (short)f2bf(u.y);
    r[2] = (short)f2bf(u.z); r[3] = (short)f2bf(u.w);
    r[4] = (short)f2bf(v.x); r[5] = (short)f2bf(v.y);
    r[6] = (short)f2bf(v.z); r[7] = (short)f2bf(v.w);
    return r;
}
__device__ __forceinline__ bf16x8 cvt8sum(const float* p, const float* q) {
    float4 u = ((const float4*)p)[0];
    float4 v = ((const float4*)p)[1];
    float4 a = ((const float4*)q)[0];
    float4 b = ((const float4*)q)[1];
    bf16x8 r;
    r[0] = (short)f2bf(u.x + a.x); r[1] = (short)f2bf(u.y + a.y);
    r[2] = (short)f2bf(u.z + a.z); r[3] = (short)f2bf(u.w + a.w);
    r[4] = (short)f2bf(v.x + b.x); r[5] = (short)f2bf(v.y + b.y);
    r[6] = (short)f2bf(v.z + b.z); r[7] = (short)f2bf(v.w + b.w);
    return r;
}

// ---------------------------------------------------------------------------
// Setup: transpose weights to bf16 [n][k] layouts via LDS 64x64 tiles
// (coalesced on both sides). grid 320, block 256.
// ---------------------------------------------------------------------------
__global__ __launch_bounds__(256) void k_trans(const float* __restrict__ la_wk,
                                               const float* __restrict__ la_wv,
                                               const float* __restrict__ mha_wo,
                                               const float* __restrict__ la_wq,
                                               const float* __restrict__ ff_w1,
                                               const float* __restrict__ ff_w2,
                                               unsigned short* __restrict__ wkb,
                                               unsigned short* __restrict__ wvb,
                                               unsigned short* __restrict__ woT,
                                               unsigned short* __restrict__ laqT,
                                               unsigned short* __restrict__ w1T,
                                               unsigned short* __restrict__ w2T) {
    __shared__ float T[64][65];
    int id = blockIdx.x, t = threadIdx.x;
    const float* src; unsigned short* dst; int R, C, tr, tc;
    if (id < 64) {
        int task = id >> 4, tile = id & 15;
        R = 256; C = 256; tr = tile >> 2; tc = tile & 3;
        src = task == 0 ? la_wk : task == 1 ? la_wv : task == 2 ? mha_wo : la_wq;
        dst = task == 0 ? wkb : task == 1 ? wvb : task == 2 ? woT : laqT;
    } else if (id < 192) {
        int tile = id - 64;
        R = 256; C = 2048; tr = tile >> 5; tc = tile & 31;
        src = ff_w1; dst = w1T;
    } else {
        int tile = id - 192;
        R = 2048; C = 256; tr = tile >> 2; tc = tile & 3;
        src = ff_w2; dst = w2T;
    }
    int r0 = tr * 64, c0 = tc * 64;
    int i = t >> 2, j0 = (t & 3) * 16;
    const float* s = src + (size_t)(r0 + i) * C + c0 + j0;
#pragma unroll
    for (int k = 0; k < 4; ++k) {
        float4 v = ((const float4*)s)[k];
        T[i][j0 + 4 * k + 0] = v.x;
        T[i][j0 + 4 * k + 1] = v.y;
        T[i][j0 + 4 * k + 2] = v.z;
        T[i][j0 + 4 * k + 3] = v.w;
    }
    __syncthreads();
    unsigned short o[16];
#pragma unroll
    for (int k = 0; k < 16; ++k) o[k] = f2bf(T[j0 + k][i]);
    unsigned short* d = dst + (size_t)(c0 + i) * R + r0 + j0;
    ((uint4*)d)[0] = *(const uint4*)&o[0];
    ((uint4*)d)[1] = *(const uint4*)&o[8];
}

// ---------------------------------------------------------------------------
// Phase A GEMM, v3: raw-barrier software pipeline. Per K-tile:
//   stage(regs->LDS b128) ; load weights(k) ; prefetch f_e(k+1) ;
//   lgkmcnt(0)+s_barrier (NO vmcnt drain -> prefetches stay in flight) ;
//   compute (pos(k+1) reload issued as pos(k) is consumed).
// Staging: 8c x 2p per thread, 2x ds_write_b128 (stride 40 ushorts: reads get
// disjoint 4-bank spans, writes ~2-way). Math bit-identical to v2.
// grid 2048 (b*64 + pt*2 + et), block 256 (4 waves, 2x2).
// ---------------------------------------------------------------------------
__global__ __launch_bounds__(256, 2) void pa_gemm(const float* __restrict__ f_e,
                                                  const float* __restrict__ pos_emb,
                                                  const unsigned short* __restrict__ wkb,
                                                  const unsigned short* __restrict__ wvb,
                                                  const float* __restrict__ bk,
                                                  const float* __restrict__ bv,
                                                  float* __restrict__ part) {
    __shared__ __align__(16) unsigned short lv[2][128 * 40];
    __shared__ float reds[2 * 128];
    __shared__ float redt[2 * 128];

    const int g  = blockIdx.x;
    const int et = g & 1;
    const int pt = (g >> 1) & 31;
    const int b  = g >> 6;
    const int p0 = pt * 128;
    const int e0 = et * 128;

    const int tid  = threadIdx.x;
    const int wave = tid >> 6;
    const int lane = tid & 63;
    const int quad = lane >> 4;
    const int l15  = lane & 15;
    const int wm = wave >> 1;
    const int wn = wave & 1;

    f32x4 accx[4][4], accv[4][4];
    const f32x4 zero4 = {0.f, 0.f, 0.f, 0.f};
#pragma unroll
    for (int i = 0; i < 4; ++i)
#pragma unroll
        for (int j = 0; j < 4; ++j) { accx[i][j] = zero4; accv[i][j] = zero4; }

    const int pp = tid & 63;       // p-pair index (p = 2*pp, 2*pp+1)
    const int cg = tid >> 6;       // c-group (8 channels per group)

    const float* feb  = f_e + (size_t)b * (256 * 4096) + p0 + 2 * pp;
    const float* posb = pos_emb + ((size_t)(p0 + wm * 64 + l15) * 32 + b) * 256 + quad * 8;
    const unsigned short* wkp = wkb + (size_t)(e0 + wn * 64 + l15) * 256 + quad * 8;
    const unsigned short* wvp = wvb + (size_t)(e0 + wn * 64 + l15) * 256 + quad * 8;

    // prologue: tile-0 f_e (8 c x 2 p per thread) and tile-0 pos fragments
    float2 nf[8];
#pragma unroll
    for (int j = 0; j < 8; ++j)
        nf[j] = *(const float2*)(feb + (size_t)(8 * cg + j) * 4096);
    float4 npp[4][2];
#pragma unroll
    for (int ms = 0; ms < 4; ++ms) {
        const float* p = posb + (size_t)ms * (16 * 32 * 256);
        npp[ms][0] = ((const float4*)p)[0];
        npp[ms][1] = ((const float4*)p)[1];
    }

#pragma unroll 1
    for (int kt = 0; kt < 8; ++kt) {
        const int c0 = kt * 32;
        unsigned short* L = lv[kt & 1];

        // stage current f_e tile: pack to bf16, 2x b128 writes
        {
            bf16x8 lo, hi;
#pragma unroll
            for (int j = 0; j < 8; ++j) {
                lo[j] = (short)f2bf(nf[j].x);
                hi[j] = (short)f2bf(nf[j].y);
            }
            *(bf16x8*)&L[(2 * pp)     * 40 + 8 * cg] = lo;
            *(bf16x8*)&L[(2 * pp + 1) * 40 + 8 * cg] = hi;
        }
        // weight fragments for THIS tile (L2-resident; latency covered by barrier wait)
        bf16x8 fk[4], fv[4];
#pragma unroll
        for (int ns = 0; ns < 4; ++ns) {
            fk[ns] = *(const bf16x8*)(wkp + (size_t)ns * (16 * 256) + c0);
            fv[ns] = *(const bf16x8*)(wvp + (size_t)ns * (16 * 256) + c0);
        }
        // prefetch next f_e tile; stays in flight ACROSS the barrier
        if (kt < 7) {
#pragma unroll
            for (int j = 0; j < 8; ++j)
                nf[j] = *(const float2*)(feb + (size_t)(c0 + 32 + 8 * cg + j) * 4096);
        }
        // raw barrier: only LDS (lgkm) drained; vmem prefetches keep flying
        asm volatile("s_waitcnt lgkmcnt(0)" ::: "memory");
        __builtin_amdgcn_s_barrier();
        asm volatile("" ::: "memory");

#pragma unroll
        for (int ms = 0; ms < 4; ++ms) {
            float4 q0 = npp[ms][0], q1 = npp[ms][1];
            // reload pos for next tile as soon as current values are copied out
            if (kt < 7) {
                const float* p = posb + (size_t)ms * (16 * 32 * 256) + c0 + 32;
                npp[ms][0] = ((const float4*)p)[0];
                npp[ms][1] = ((const float4*)p)[1];
            }
            int row = wm * 64 + ms * 16 + l15;
            uint4 avu = *(const uint4*)&L[row * 40 + quad * 8];
            bf16x8 av = *(const bf16x8*)&avu;
            // X fragment = bf16(f32(V) + pos)  (identical math to v1/v2)
            bf16x8 ax;
            ax[0] = (short)f2bf(__uint_as_float(avu.x << 16)          + q0.x);
            ax[1] = (short)f2bf(__uint_as_float(avu.x & 0xffff0000u)  + q0.y);
            ax[2] = (short)f2bf(__uint_as_float(avu.y << 16)          + q0.z);
            ax[3] = (short)f2bf(__uint_as_float(avu.y & 0xffff0000u)  + q0.w);
            ax[4] = (short)f2bf(__uint_as_float(avu.z << 16)          + q1.x);
            ax[5] = (short)f2bf(__uint_as_float(avu.z & 0xffff0000u)  + q1.y);
            ax[6] = (short)f2bf(__uint_as_float(avu.w << 16)          + q1.z);
            ax[7] = (short)f2bf(__uint_as_float(avu.w & 0xffff0000u)  + q1.w);
#pragma unroll
            for (int ns = 0; ns < 4; ++ns) {
                accx[ms][ns] = __builtin_amdgcn_mfma_f32_16x16x32_bf16(ax, fk[ns], accx[ms][ns], 0, 0, 0);
                accv[ms][ns] = __builtin_amdgcn_mfma_f32_16x16x32_bf16(av, fv[ns], accv[ms][ns], 0, 0, 0);
            }
        }
    }

#pragma unroll
    for (int ns = 0; ns < 4; ++ns) {
        int nloc = wn * 64 + ns * 16 + l15;
        float bkv = bk[e0 + nloc];
        float bvv = bv[e0 + nloc];
        float ps = 0.f, pt_ = 0.f;
#pragma unroll
        for (int ms = 0; ms < 4; ++ms)
#pragma unroll
            for (int r = 0; r < 4; ++r) {
                float ex = __expf(accx[ms][ns][r] + bkv);
                float vv = accv[ms][ns][r] + bvv;
                ps += ex;
                pt_ += ex * vv;
            }
        ps  += __shfl_xor(ps, 16);  ps  += __shfl_xor(ps, 32);
        pt_ += __shfl_xor(pt_, 16); pt_ += __shfl_xor(pt_, 32);
        if (lane < 16) { reds[wm * 128 + nloc] = ps; redt[wm * 128 + nloc] = pt_; }
    }
    __syncthreads();
    if (tid < 128) {
        float s = reds[tid] + reds[128 + tid];
        float t = redt[tid] + redt[128 + tid];
        part[(size_t)g * 256 + tid] = s;
        part[(size_t)g * 256 + 128 + tid] = t;
    }
}

__global__ __launch_bounds__(256) void pa_reduce(const float* __restrict__ part,
                                                 float* __restrict__ ctx) {
    int e = blockIdx.x, tid = threadIdx.x;
    int et = e >> 7, n = e & 127;
    float s = 0.f, t = 0.f;
#pragma unroll
    for (int j = 0; j < 4; ++j) {
        int q = tid * 4 + j;
        const float* p = part + (size_t)(q * 2 + et) * 256 + n;
        s += p[0];
        t += p[128];
    }
    int wave = tid >> 6, lane = tid & 63;
#pragma unroll
    for (int o = 1; o < 64; o <<= 1) { s += __shfl_xor(s, o); t += __shfl_xor(t, o); }
    __shared__ float rs[4], rt[4];
    if (lane == 0) { rs[wave] = s; rt[wave] = t; }
    __syncthreads();
    if (tid == 0) {
        float S = rs[0] + rs[1] + rs[2] + rs[3];
        float T = rt[0] + rt[1] + rt[2] + rt[3];
        ctx[e] = T / S;
    }
}

// ---------------------------------------------------------------------------
// Query positional encoding qp[27][256]. grid 27, block 256.
// ---------------------------------------------------------------------------
__global__ __launch_bounds__(256) void k_qpos(float* __restrict__ qp) {
    int n = blockIdx.x, e = threadIdx.x;
    int q9 = n % 9;
    int y = q9 / 3, x = q9 % 3;
    float pos; int idx;
    if (e < 128) { pos = (float)(y + 1); idx = e; }
    else         { pos = (float)(x + 1); idx = e - 128; }
    int j = idx >> 1;
    float inv = expf(-(float)j * 0.14391156831212787f);
    float arg = pos * inv;
    qp[(size_t)n * 256 + e] = (idx & 1) ? cosf(arg) : sinf(arg);
}

// kp/vp = shape_map @ mha_wk/wv + b. grid 54, block 256.
__global__ __launch_bounds__(256) void k_kvproj(const float* __restrict__ sm,
                                                const float* __restrict__ wk,
                                                const float* __restrict__ bk,
                                                const float* __restrict__ wv,
                                                const float* __restrict__ bv,
                                                float* __restrict__ kp,
                                                float* __restrict__ vp) {
    int g = blockIdx.x;
    int n = g % 27, which = g / 27;
    int e = threadIdx.x;
    const float* W = which ? wv : wk;
    const float* B = which ? bv : bk;
    float* O = which ? vp : kp;
    const float* row = sm + (size_t)n * 256;
    float acc = 0.f;
    for (int c = 0; c < 256; ++c) acc += row[c] * W[(size_t)c * 256 + e];
    O[(size_t)n * 256 + e] = acc + B[e];
}

// MT[h][s][c] = scale * sum_d wq[c][h*32+d]*kp[s][h*32+d]; cst[h][s] likewise for bq.
// grid 256 (h*32+s), block 256 (c)
__global__ __launch_bounds__(256) void k_mt(const float* __restrict__ wq,
                                            const float* __restrict__ bq,
                                            const float* __restrict__ kp,
                                            unsigned short* __restrict__ MT,
                                            float* __restrict__ cst) {
    int h = blockIdx.x >> 5, s = blockIdx.x & 31;
    int c = threadIdx.x;
    const float SC = 0.17677669529663687f;   // 1/sqrt(32)
    if (s < 27) {
        float a = 0.f;
#pragma unroll
        for (int d = 0; d < 32; ++d)
            a += wq[(size_t)c * 256 + h * 32 + d] * kp[(size_t)s * 256 + h * 32 + d];
        MT[((size_t)(h * 32 + s)) * 256 + c] = f2bf(a * SC);
        if (c == 0) {
            float cb = 0.f;
#pragma unroll
            for (int d = 0; d < 32; ++d) cb += bq[h * 32 + d] * kp[(size_t)s * 256 + h * 32 + d];
            cst[h * 32 + s] = cb * SC;
        }
    } else {
        MT[((size_t)(h * 32 + s)) * 256 + c] = 0;
        if (c == 0) cst[h * 32 + s] = -1e30f;
    }
}

// vpT[h][d][s] = bf16(vp[s][h*32+d]) (s>=27 -> 0). grid 8, block 256.
__global__ __launch_bounds__(256) void k_vpt(const float* __restrict__ vp,
                                             unsigned short* __restrict__ vpT) {
    int h = blockIdx.x, t = threadIdx.x;
    int s = t & 31;
#pragma unroll
    for (int i = 0; i < 4; ++i) {
        int d = (t >> 5) + 8 * i;
        vpT[((size_t)(h * 32 + d)) * 32 + s] = (s < 27) ? f2bf(vp[(size_t)s * 256 + h * 32 + d]) : (unsigned short)0;
    }
}

// F0[r][e] = shape_map[r>>5][e]. grid 864, block 256.
__global__ __launch_bounds__(256) void k_finit(const float* __restrict__ sm,
                                               float* __restrict__ F) {
    int r = blockIdx.x, e = threadIdx.x;
    F[(size_t)r * 256 + e] = sm[(size_t)(r >> 5) * 256 + e];
}

// ---------------------------------------------------------------------------
// B1: fused qproj + attention per (b,h). grid 256, block 256 (4 waves).
// ---------------------------------------------------------------------------
__global__ __launch_bounds__(256) void b1_attn(const float* __restrict__ F,
                                               const float* __restrict__ qp,
                                               const unsigned short* __restrict__ MT,
                                               const float* __restrict__ cst,
                                               const unsigned short* __restrict__ vpT,
                                               float* __restrict__ aout) {
    __shared__ float S[32][33];
    __shared__ __align__(16) unsigned short Pb[32][40];
    int b = blockIdx.x >> 3, h = blockIdx.x & 7;
    int tid = threadIdx.x, wave = tid >> 6, lane = tid & 63;
    int quad = lane >> 4, l15 = lane & 15;
    int lt = wave >> 1, st = wave & 1;
    const f32x4 z4 = {0.f, 0.f, 0.f, 0.f};
    f32x4 acc = z4;
    int l = lt * 16 + l15;
    bool lok = (l < 27);
    const float* xF = F + (size_t)(l * 32 + b) * 256;
    const float* xq = qp + (size_t)l * 256;
    const unsigned short* Bp = MT + (size_t)(h * 32 + st * 16 + l15) * 256;
#pragma unroll
    for (int kt = 0; kt < 8; ++kt) {
        int c = kt * 32 + quad * 8;
        bf16x8 a;
        if (lok) a = cvt8sum(xF + c, xq + c);
        else {
#pragma unroll
            for (int i = 0; i < 8; ++i) a[i] = 0;
        }
        bf16x8 bb = *(const bf16x8*)(Bp + c);
        acc = __builtin_amdgcn_mfma_f32_16x16x32_bf16(a, bb, acc, 0, 0, 0);
    }
    float cstv = cst[h * 32 + st * 16 + l15];
#pragma unroll
    for (int r = 0; r < 4; ++r) S[lt * 16 + quad * 4 + r][st * 16 + l15] = acc[r] + cstv;
    __syncthreads();
    if (tid < 32) {
        float pv[32];
        float m = -1e30f;
#pragma unroll
        for (int s = 0; s < 32; ++s) { pv[s] = S[tid][s]; m = fmaxf(m, pv[s]); }
        float sum = 0.f;
#pragma unroll
        for (int s = 0; s < 32; ++s) { pv[s] = __expf(pv[s] - m); sum += pv[s]; }
        float inv = 1.f / sum;
#pragma unroll
        for (int s = 0; s < 32; ++s) Pb[tid][s] = f2bf(pv[s] * inv);
    }
    __syncthreads();
    bf16x8 a2 = *(const bf16x8*)&Pb[lt * 16 + l15][quad * 8];
    bf16x8 b2 = *(const bf16x8*)(vpT + (size_t)(h * 32 + st * 16 + l15) * 32 + quad * 8);
    f32x4 o = __builtin_amdgcn_mfma_f32_16x16x32_bf16(a2, b2, z4, 0, 0, 0);
#pragma unroll
    for (int r = 0; r < 4; ++r) {
        int ll = lt * 16 + quad * 4 + r;
        if (ll < 27) aout[(size_t)(ll * 32 + b) * 256 + h * 32 + st * 16 + l15] = o[r];
    }
}

// ---------------------------------------------------------------------------
// B2: fused oproj + LN1 + linear-attn + LN2 for 16-row tile. grid 54, block 256.
// ---------------------------------------------------------------------------
__global__ __launch_bounds__(256) void b2_mid(const float* __restrict__ aout,
                                              const unsigned short* __restrict__ woT,
                                              const float* __restrict__ bo,
                                              float* __restrict__ F,
                                              const float* __restrict__ g1,
                                              const float* __restrict__ b1v,
                                              const float* __restrict__ qp,
                                              const unsigned short* __restrict__ laqT,
                                              const float* __restrict__ labq,
                                              const float* __restrict__ ctx,
                                              const float* __restrict__ g2,
                                              const float* __restrict__ b2v) {
    __shared__ __align__(16) unsigned short X1b[16][264];
    __shared__ float r1s[4][16], r1q[4][16], rm[4][16], rp[4][16], r2s[4][16], r2q[4][16];
    int r0 = blockIdx.x * 16;
    int lrow = r0 >> 5;
    int tid = threadIdx.x, w = tid >> 6, lane = tid & 63;
    int quad = lane >> 4, l15 = lane & 15;
    const f32x4 z4 = {0.f, 0.f, 0.f, 0.f};
    f32x4 acc[4] = {z4, z4, z4, z4};
    const float* Ap = aout + (size_t)(r0 + l15) * 256;
#pragma unroll
    for (int kt = 0; kt < 8; ++kt) {
        int c = kt * 32 + quad * 8;
        bf16x8 a = cvt8(Ap + c);
#pragma unroll
        for (int nt = 0; nt < 4; ++nt) {
            bf16x8 bb = *(const bf16x8*)(woT + (size_t)(w * 64 + nt * 16 + l15) * 256 + c);
            acc[nt] = __builtin_amdgcn_mfma_f32_16x16x32_bf16(a, bb, acc[nt], 0, 0, 0);
        }
    }
    int e_[4];
#pragma unroll
    for (int nt = 0; nt < 4; ++nt) e_[nt] = w * 64 + nt * 16 + l15;
    float val[4][4];
#pragma unroll
    for (int nt = 0; nt < 4; ++nt) {
        float bov = bo[e_[nt]];
#pragma unroll
        for (int r = 0; r < 4; ++r) {
            int row = quad * 4 + r;
            val[nt][r] = acc[nt][r] + bov + F[(size_t)(r0 + row) * 256 + e_[nt]];
        }
    }
    // LN1 reduce
#pragma unroll
    for (int r = 0; r < 4; ++r) {
        float s = val[0][r] + val[1][r] + val[2][r] + val[3][r];
        float q = val[0][r] * val[0][r] + val[1][r] * val[1][r] + val[2][r] * val[2][r] + val[3][r] * val[3][r];
#pragma unroll
        for (int o = 1; o < 16; o <<= 1) { s += __shfl_xor(s, o); q += __shfl_xor(q, o); }
        if (l15 == 0) { r1s[w][quad * 4 + r] = s; r1q[w][quad * 4 + r] = q; }
    }
    __syncthreads();
#pragma unroll
    for (int r = 0; r < 4; ++r) {
        int row = quad * 4 + r;
        float S = r1s[0][row] + r1s[1][row] + r1s[2][row] + r1s[3][row];
        float Q = r1q[0][row] + r1q[1][row] + r1q[2][row] + r1q[3][row];
        float mean = S * (1.f / 256.f);
        float var  = Q * (1.f / 256.f) - mean * mean;
        float rs   = rsqrtf(var + EPS_);
#pragma unroll
        for (int nt = 0; nt < 4; ++nt) {
            int e = e_[nt];
            float f1 = (val[nt][r] - mean) * rs * g1[e] + b1v[e];
            X1b[row][e] = f2bf(f1 + qp[(size_t)lrow * 256 + e]);
            val[nt][r] = f1;   // keep F1 in regs for residual
        }
    }
    __syncthreads();
    // GEMM2: (F1+qp) @ la_wq
    f32x4 acc2[4] = {z4, z4, z4, z4};
#pragma unroll
    for (int kt = 0; kt < 8; ++kt) {
        int c = kt * 32 + quad * 8;
        bf16x8 a = *(const bf16x8*)&X1b[l15][c];
#pragma unroll
        for (int nt = 0; nt < 4; ++nt) {
            bf16x8 bb = *(const bf16x8*)(laqT + (size_t)(w * 64 + nt * 16 + l15) * 256 + c);
            acc2[nt] = __builtin_amdgcn_mfma_f32_16x16x32_bf16(a, bb, acc2[nt], 0, 0, 0);
        }
    }
    float y[4][4];
#pragma unroll
    for (int nt = 0; nt < 4; ++nt) {
        float bqv = labq[e_[nt]];
#pragma unroll
        for (int r = 0; r < 4; ++r) y[nt][r] = (acc2[nt][r] + bqv) * 0.0625f;
    }
    // softmax over e per row: max
#pragma unroll
    for (int r = 0; r < 4; ++r) {
        float m = fmaxf(fmaxf(y[0][r], y[1][r]), fmaxf(y[2][r], y[3][r]));
#pragma unroll
        for (int o = 1; o < 16; o <<= 1) m = fmaxf(m, __shfl_xor(m, o));
        if (l15 == 0) rm[w][quad * 4 + r] = m;
    }
    __syncthreads();
    float p[4][4];
#pragma unroll
    for (int r = 0; r < 4; ++r) {
        int row = quad * 4 + r;
        float M = fmaxf(fmaxf(rm[0][row], rm[1][row]), fmaxf(rm[2][row], rm[3][row]));
        float ps = 0.f;
#pragma unroll
        for (int nt = 0; nt < 4; ++nt) { p[nt][r] = __expf(y[nt][r] - M); ps += p[nt][r]; }
#pragma unroll
        for (int o = 1; o < 16; o <<= 1) ps += __shfl_xor(ps, o);
        if (l15 == 0) rp[w][row] = ps;
    }
    __syncthreads();
#pragma unroll
    for (int r = 0; r < 4; ++r) {
        int row = quad * 4 + r;
        float Ssum = rp[0][row] + rp[1][row] + rp[2][row] + rp[3][row];
        float inv = 1.f / Ssum;
#pragma unroll
        for (int nt = 0; nt < 4; ++nt)
            val[nt][r] = val[nt][r] + (p[nt][r] * inv) * ctx[e_[nt]];
    }
    // LN2
#pragma unroll
    for (int r = 0; r < 4; ++r) {
        float s = val[0][r] + val[1][r] + val[2][r] + val[3][r];
        float q = val[0][r] * val[0][r] + val[1][r] * val[1][r] + val[2][r] * val[2][r] + val[3][r] * val[3][r];
#pragma unroll
        for (int o = 1; o < 16; o <<= 1) { s += __shfl_xor(s, o); q += __shfl_xor(q, o); }
        if (l15 == 0) { r2s[w][quad * 4 + r] = s; r2q[w][quad * 4 + r] = q; }
    }
    __syncthreads();
#pragma unroll
    for (int r = 0; r < 4; ++r) {
        int row = quad * 4 + r;
        float S = r2s[0][row] + r2s[1][row] + r2s[2][row] + r2s[3][row];
        float Q = r2q[0][row] + r2q[1][row] + r2q[2][row] + r2q[3][row];
        float mean = S * (1.f / 256.f);
        float var  = Q * (1.f / 256.f) - mean * mean;
        float rs   = rsqrtf(var + EPS_);
#pragma unroll
        for (int nt = 0; nt < 4; ++nt) {
            int e = e_[nt];
            F[(size_t)(r0 + row) * 256 + e] = (val[nt][r] - mean) * rs * g2[e] + b2v[e];
        }
    }
}

// ---------------------------------------------------------------------------
// B3: FFN1 H = gelu(F @ w1 + b1), bf16 out. grid 1728 (54 m x 32 n), block 256.
// ---------------------------------------------------------------------------
__global__ __launch_bounds__(256) void b3_ffn1(const float* __restrict__ F,
                                               const unsigned short* __restrict__ w1T,
                                               const float* __restrict__ fb1,
                                               unsigned short* __restrict__ Hb) {
    int bm = blockIdx.x >> 5, bn = blockIdx.x & 31;
    int tid = threadIdx.x, w = tid >> 6, lane = tid & 63;
    int quad = lane >> 4, l15 = lane & 15;
    int r0 = bm * 16;
    int n0 = bn * 64 + w * 16;
    const f32x4 z4 = {0.f, 0.f, 0.f, 0.f};
    f32x4 acc = z4;
    const float* Ap = F + (size_t)(r0 + l15) * 256;
    const unsigned short* Bp = w1T + (size_t)(n0 + l15) * 256;
#pragma unroll
    for (int kt = 0; kt < 8; ++kt) {
        int c = kt * 32 + quad * 8;
        bf16x8 a = cvt8(Ap + c);
        bf16x8 bb = *(const bf16x8*)(Bp + c);
        acc = __builtin_amdgcn_mfma_f32_16x16x32_bf16(a, bb, acc, 0, 0, 0);
    }
    int e = n0 + l15;
    float bv = fb1[e];
#pragma unroll
    for (int r = 0; r < 4; ++r) {
        float hh = acc[r] + bv;
        float g = 0.5f * hh * (1.f + erff(hh * 0.70710678118654752f));
        Hb[(size_t)(r0 + quad * 4 + r) * 2048 + e] = f2bf(g);
    }
}

// ---------------------------------------------------------------------------
// B4: FFN2 + bias + residual + LN3 + output write. grid 54, block 256.
// ---------------------------------------------------------------------------
__global__ __launch_bounds__(256) void b4_ffn2(const unsigned short* __restrict__ Hb,
                                               const unsigned short* __restrict__ w2T,
                                               const float* __restrict__ fb2,
                                               float* __restrict__ F,
                                               const float* __restrict__ g3,
                                               const float* __restrict__ b3v,
                                               float* __restrict__ out,
                                               int step) {
    __shared__ float r3s[4][16], r3q[4][16];
    int r0 = blockIdx.x * 16;
    int tid = threadIdx.x, w = tid >> 6, lane = tid & 63;
    int quad = lane >> 4, l15 = lane & 15;
    const f32x4 z4 = {0.f, 0.f, 0.f, 0.f};
    f32x4 acc[4] = {z4, z4, z4, z4};
    const unsigned short* Ap = Hb + (size_t)(r0 + l15) * 2048;
#pragma unroll 4
    for (int kt = 0; kt < 64; ++kt) {
        int c = kt * 32 + quad * 8;
        bf16x8 a = *(const bf16x8*)(Ap + c);
#pragma unroll
        for (int nt = 0; nt < 4; ++nt) {
            bf16x8 bb = *(const bf16x8*)(w2T + (size_t)(w * 64 + nt * 16 + l15) * 2048 + c);
            acc[nt] = __builtin_amdgcn_mfma_f32_16x16x32_bf16(a, bb, acc[nt], 0, 0, 0);
        }
    }
    int e_[4];
#pragma unroll
    for (int nt = 0; nt < 4; ++nt) e_[nt] = w * 64 + nt * 16 + l15;
    float val[4][4];
#pragma unroll
    for (int nt = 0; nt < 4; ++nt) {
        float bv = fb2[e_[nt]];
#pragma unroll
        for (int r = 0; r < 4; ++r) {
            int row = quad * 4 + r;
            val[nt][r] = acc[nt][r] + bv + F[(size_t)(r0 + row) * 256 + e_[nt]];
        }
    }
#pragma unroll
    for (int r = 0; r < 4; ++r) {
        float s = val[0][r] + val[1][r] + val[2][r] + val[3][r];
        float q = val[0][r] * val[0][r] + val[1][r] * val[1][r] + val[2][r] * val[2][r] + val[3][r] * val[3][r];
#pragma unroll
        for (int o = 1; o < 16; o <<= 1) { s += __shfl_xor(s, o); q += __shfl_xor(q, o); }
        if (l15 == 0) { r3s[w][quad * 4 + r] = s; r3q[w][quad * 4 + r] = q; }
    }
    __syncthreads();
#pragma unroll
    for (int r = 0; r < 4; ++r) {
        int row = quad * 4 + r;
        float S = r3s[0][row] + r3s[1][row] + r3s[2][row] + r3s[3][row];
        float Q = r3q[0][row] + r3q[1][row] + r3q[2][row] + r3q[3][row];
        float mean = S * (1.f / 256.f);
        float var  = Q * (1.f / 256.f) - mean * mean;
        float rs   = rsqrtf(var + EPS_);
#pragma unroll
        for (int nt = 0; nt < 4; ++nt) {
            int e = e_[nt];
            float o = (val[nt][r] - mean) * rs * g3[e] + b3v[e];
            F[(size_t)(r0 + row) * 256 + e] = o;
            out[(size_t)step * 221184 + (size_t)(r0 + row) * 256 + e] = o;
        }
    }
}

// ---------------------------------------------------------------------------
extern "C" void kernel_launch(void* const* d_in, const int* in_sizes, int n_in,
                              void* d_out, int out_size, void* d_ws, size_t ws_size,
                              hipStream_t stream) {
    const float* f_e     = (const float*)d_in[0];
    const float* pos_emb = (const float*)d_in[1];
    const float* sm      = (const float*)d_in[3];
    const float* mha_wq  = (const float*)d_in[4];
    const float* mha_bq  = (const float*)d_in[5];
    const float* mha_wk  = (const float*)d_in[6];
    const float* mha_bk  = (const float*)d_in[7];
    const float* mha_wv  = (const float*)d_in[8];
    const float* mha_bv  = (const float*)d_in[9];
    const float* mha_wo  = (const float*)d_in[10];
    const float* mha_bo  = (const float*)d_in[11];
    const float* la_wq   = (const float*)d_in[12];
    const float* la_bq   = (const float*)d_in[13];
    const float* la_wk   = (const float*)d_in[14];
    const float* la_bk   = (const float*)d_in[15];
    const float* la_wv   = (const float*)d_in[16];
    const float* la_bv   = (const float*)d_in[17];
    const float* ff_w1   = (const float*)d_in[18];
    const float* ff_b1   = (const float*)d_in[19];
    const float* ff_w2   = (const float*)d_in[20];
    const float* ff_b2   = (const float*)d_in[21];
    const float* n1_g    = (const float*)d_in[22];
    const float* n1_b    = (const float*)d_in[23];
    const float* n2_g    = (const float*)d_in[24];
    const float* n2_b    = (const float*)d_in[25];
    const float* n3_g    = (const float*)d_in[26];
    const float* n3_b    = (const float*)d_in[27];

    float* ws = (float*)d_ws;
    float* part = ws + WS_PART;
    float* ctx  = ws + WS_CTX;
    float* qp   = ws + WS_QP;
    float* kp   = ws + WS_KP;
    float* vp   = ws + WS_VP;
    float* F    = ws + WS_F;
    float* aout = ws + WS_ATTN;
    unsigned short* Hb   = (unsigned short*)(ws + WS_H);
    unsigned short* wkb  = (unsigned short*)(ws + WS_WKB);
    unsigned short* wvb  = (unsigned short*)(ws + WS_WVB);
    unsigned short* woT  = (unsigned short*)(ws + WS_WOT);
    unsigned short* laqT = (unsigned short*)(ws + WS_LAQT);
    unsigned short* w1T  = (unsigned short*)(ws + WS_W1T);
    unsigned short* w2T  = (unsigned short*)(ws + WS_W2T);
    unsigned short* MT   = (unsigned short*)(ws + WS_MT);
    unsigned short* vpT  = (unsigned short*)(ws + WS_VPT);
    float* cst = ws + WS_CST;

    float* out = (float*)d_out;

    // setup
    k_trans<<<320, 256, 0, stream>>>(la_wk, la_wv, mha_wo, la_wq, ff_w1, ff_w2,
                                     wkb, wvb, woT, laqT, w1T, w2T);
    k_qpos<<<27, 256, 0, stream>>>(qp);
    k_kvproj<<<54, 256, 0, stream>>>(sm, mha_wk, mha_bk, mha_wv, mha_bv, kp, vp);
    k_mt<<<256, 256, 0, stream>>>(mha_wq, mha_bq, kp, MT, cst);
    k_vpt<<<8, 256, 0, stream>>>(vp, vpT);
    k_finit<<<864, 256, 0, stream>>>(sm, F);

    // phase A
    pa_gemm<<<2048, 256, 0, stream>>>(f_e, pos_emb, wkb, wvb, la_bk, la_bv, part);
    pa_reduce<<<256, 256, 0, stream>>>(part, ctx);

    // phase B: 3 decoder steps
    for (int s = 0; s < 3; ++s) {
        b1_attn<<<256, 256, 0, stream>>>(F, qp, MT, cst, vpT, aout);
        b2_mid<<<54, 256, 0, stream>>>(aout, woT, mha_bo, F, n1_g, n1_b, qp,
                                       laqT, la_bq, ctx, n2_g, n2_b);
        b3_ffn1<<<1728, 256, 0, stream>>>(F, w1T, ff_b1, Hb);
        b4_ffn2<<<54, 256, 0, stream>>>(Hb, w2T, ff_b2, F, n3_g, n3_b, out, s);
    }
}